// Round 2
// baseline (720.531 us; speedup 1.0000x reference)
//
#include <hip/hip_runtime.h>
#include <hip/hip_bf16.h>
#include <cstdint>
#include <cstddef>

#define N_TOK 16384
#define DIM   1024
#define NEXP  64
#define CAPACITY 640

typedef __bf16 bf16x8 __attribute__((ext_vector_type(8)));
typedef float  f32x4  __attribute__((ext_vector_type(4)));

__device__ __forceinline__ unsigned short f2bf(float f) {
    union { float f; unsigned int u; } a; a.f = f;
    unsigned int r = a.u + 0x7FFFu + ((a.u >> 16) & 1u);  // RTNE
    return (unsigned short)(r >> 16);
}

typedef __attribute__((address_space(3))) void       lds_void;
typedef const __attribute__((address_space(1))) void glb_void;
__device__ __forceinline__ void gload_lds16(const void* g, void* l) {
    __builtin_amdgcn_global_load_lds((glb_void*)g, (lds_void*)l, 16, 0, 0);
}

// ---------------------------------------------------------------------------
// Phase 0: We fp32 [e][k][n] -> Web bf16 [e][n][k]  (convert + transpose).
// 64x64 tile per block; LDS holds k-pairs packed into dwords, stride 33 words.
// ---------------------------------------------------------------------------
__global__ __launch_bounds__(256) void convert_we(
    const float* __restrict__ We, unsigned short* __restrict__ Web)
{
    __shared__ unsigned int ts[64 * 33];   // [n][k-pair] packed bf16x2
    const int bid = blockIdx.x;
    const int e  = bid >> 8;
    const int kb = (bid >> 4) & 15, nb = bid & 15;
    const int k0 = kb * 64, n0 = nb * 64;
    const int tid = threadIdx.x;

    // read phase: thread = (rp = tid>>3: k-row pair, ng = tid&7: 8-wide n group)
    {
        const int rp = tid >> 3, ng = tid & 7;
        const float* r0 = We + (size_t)e * DIM * DIM + (size_t)(k0 + 2 * rp) * DIM + n0 + ng * 8;
        float4 a0 = *(const float4*)(r0);
        float4 a1 = *(const float4*)(r0 + 4);
        float4 b0 = *(const float4*)(r0 + DIM);
        float4 b1 = *(const float4*)(r0 + DIM + 4);
        const float* af = (const float*)&a0;
        const float* bf = (const float*)&b0;
#pragma unroll
        for (int i = 0; i < 4; i++)
            ts[(ng * 8 + i) * 33 + rp] = (unsigned int)f2bf(af[i]) | ((unsigned int)f2bf(bf[i]) << 16);
        af = (const float*)&a1; bf = (const float*)&b1;
#pragma unroll
        for (int i = 0; i < 4; i++)
            ts[(ng * 8 + 4 + i) * 33 + rp] = (unsigned int)f2bf(af[i]) | ((unsigned int)f2bf(bf[i]) << 16);
    }
    __syncthreads();
    // write phase: thread = (nr = tid>>2: n row, kg = tid&3: 16-wide k group)
    {
        const int nr = tid >> 2, kg = tid & 3;
        unsigned int r[8];
#pragma unroll
        for (int i = 0; i < 8; i++) r[i] = ts[nr * 33 + kg * 8 + i];
        unsigned int* dst = (unsigned int*)Web +
            (((size_t)(e * 1024 + n0 + nr) * DIM + k0) >> 1) + kg * 8;
        *(uint4*)(dst)     = make_uint4(r[0], r[1], r[2], r[3]);
        *(uint4*)(dst + 4) = make_uint4(r[4], r[5], r[6], r[7]);
    }
}

// ---------------------------------------------------------------------------
// Phase 1: router GEMM (fp32) + top-2 + softmax gates + x -> bf16 conversion.
// ---------------------------------------------------------------------------
__global__ __launch_bounds__(256) void router_kernel(
    const float* __restrict__ x, const float* __restrict__ Wr,
    const float* __restrict__ br, unsigned short* __restrict__ xb,
    int* __restrict__ top2i, float* __restrict__ gates2)
{
    __shared__ float xs[64][68];
    __shared__ float wT[64][68];
    const int tid = threadIdx.x;
    const int t0  = blockIdx.x * 64;
    const int tm  = tid >> 4;
    const int te  = tid & 15;

    float acc[4][4];
#pragma unroll
    for (int i = 0; i < 4; i++)
#pragma unroll
        for (int j = 0; j < 4; j++) acc[i][j] = 0.f;

    for (int ks = 0; ks < DIM; ks += 64) {
        __syncthreads();
#pragma unroll
        for (int l = 0; l < 4; l++) {
            int row = l * 16 + tm;
            int col = te * 4;
            float4 v = *(const float4*)(x + (size_t)(t0 + row) * DIM + ks + col);
            *(float4*)&xs[row][col] = v;
            ushort4 b = make_ushort4(f2bf(v.x), f2bf(v.y), f2bf(v.z), f2bf(v.w));
            *(ushort4*)(xb + (size_t)(t0 + row) * DIM + ks + col) = b;
        }
#pragma unroll
        for (int l = 0; l < 4; l++) {
            int kr = l * 16 + tm;
            int ec = te * 4;
            float4 v = *(const float4*)(Wr + (size_t)(ks + kr) * NEXP + ec);
            wT[ec + 0][kr] = v.x; wT[ec + 1][kr] = v.y;
            wT[ec + 2][kr] = v.z; wT[ec + 3][kr] = v.w;
        }
        __syncthreads();
#pragma unroll 4
        for (int kk = 0; kk < 64; kk += 4) {
            float4 xv[4], wv[4];
#pragma unroll
            for (int i = 0; i < 4; i++) xv[i] = *(float4*)&xs[tm + i * 16][kk];
#pragma unroll
            for (int j = 0; j < 4; j++) wv[j] = *(float4*)&wT[te + j * 16][kk];
#pragma unroll
            for (int i = 0; i < 4; i++)
#pragma unroll
                for (int j = 0; j < 4; j++)
                    acc[i][j] += xv[i].x * wv[j].x + xv[i].y * wv[j].y +
                                 xv[i].z * wv[j].z + xv[i].w * wv[j].w;
        }
    }
    __syncthreads();
#pragma unroll
    for (int i = 0; i < 4; i++)
#pragma unroll
        for (int j = 0; j < 4; j++)
            xs[tm + i * 16][te + j * 16] = acc[i][j] + br[te + j * 16];
    __syncthreads();
    if (tid < 64) {
        int n = t0 + tid;
        float v1 = -1e30f, v2 = -1e30f; int i1 = 0, i2 = 0;
        for (int e = 0; e < 64; e++) {
            float v = xs[tid][e];
            if (v > v1)      { v2 = v1; i2 = i1; v1 = v; i1 = e; }
            else if (v > v2) { v2 = v;  i2 = e; }
        }
        float g0 = 1.f / (1.f + expf(v2 - v1));
        top2i[n * 2 + 0] = i1; top2i[n * 2 + 1] = i2;
        gates2[n * 2 + 0] = g0; gates2[n * 2 + 1] = 1.f - g0;
    }
}

// ---------------------------------------------------------------------------
// Phase 2: stable counting-sort slot assignment (matches reference cumsum).
// ---------------------------------------------------------------------------
__global__ __launch_bounds__(256) void hist_kernel(
    const int* __restrict__ top2i, int* __restrict__ hist)
{
    __shared__ int cnt[NEXP];
    int tid = threadIdx.x;
    if (tid < NEXP) cnt[tid] = 0;
    __syncthreads();
    int p = blockIdx.x * 256 + tid;
    int k = p >> 14, n = p & 16383;
    int e = top2i[n * 2 + k];
    atomicAdd(&cnt[e], 1);
    __syncthreads();
    if (tid < NEXP) hist[blockIdx.x * NEXP + tid] = cnt[tid];
}

__global__ __launch_bounds__(64) void scan_kernel(
    const int* __restrict__ hist, int* __restrict__ pre, int* __restrict__ cntc)
{
    int e = threadIdx.x;
    int run = 0;
#pragma unroll 8
    for (int c = 0; c < 128; c++) {
        pre[c * NEXP + e] = run;
        run += hist[c * NEXP + e];
    }
    cntc[e] = run < CAPACITY ? run : CAPACITY;
}

__global__ __launch_bounds__(64) void rank_kernel(
    const int* __restrict__ top2i, const float* __restrict__ gates2,
    const int* __restrict__ pre, int* __restrict__ list_tok,
    float* __restrict__ list_gate)
{
    int lane = threadIdx.x;
    int c = blockIdx.x;
    int cnt_reg = pre[c * NEXP + lane];
    unsigned long long below = (1ull << lane) - 1ull;
    for (int r = 0; r < 4; r++) {
        int p = c * 256 + r * 64 + lane;
        int k = p >> 14, n = p & 16383;
        int e = top2i[n * 2 + k];
        int slot = 0;
#pragma unroll 1
        for (int q = 0; q < NEXP; q++) {
            unsigned long long mask = __ballot(e == q);
            int base = __shfl(cnt_reg, q);
            if (e == q) slot = base + __popcll(mask & below);
            if (lane == q) cnt_reg += (int)__popcll(mask);
        }
        if (slot < CAPACITY) {
            list_tok[e * CAPACITY + slot]  = n;
            list_gate[e * CAPACITY + slot] = gates2[n * 2 + k];
        }
    }
}

// ---------------------------------------------------------------------------
// Phase 3 (fast): grouped GEMM, A & B via global_load_lds w/ XOR-swizzled LDS.
// A = gathered bf16 token rows [m][k]; B = Web bf16 [n][k]. BK=64.
// ---------------------------------------------------------------------------
#define MT 128
#define NT 128
#define BKF 64

__global__ __launch_bounds__(256) void moe_gemm_bt(
    const unsigned short* __restrict__ xb, const unsigned short* __restrict__ Web,
    const int* __restrict__ list_tok, const float* __restrict__ list_gate,
    const int* __restrict__ cntc, float* __restrict__ out)
{
    const int bid = blockIdx.x;
    const int e   = bid / 40;
    const int rem = bid % 40;
    const int mt  = rem >> 3;
    const int nt  = rem & 7;
    const int cnt = cntc[e];
    if (mt * MT >= cnt) return;
    int valid = cnt - mt * MT; if (valid > MT) valid = MT;

    __shared__ unsigned short As[MT * BKF];   // swizzled: granule s = q ^ (row&7)
    __shared__ unsigned short Bs[NT * BKF];
    __shared__ int   tok_s[MT];
    __shared__ float gate_s[MT];

    const int tid = threadIdx.x;
    if (tid < MT) {
        int slot = mt * MT + tid;
        bool v = tid < valid;
        tok_s[tid]  = v ? list_tok[e * CAPACITY + slot]  : list_tok[e * CAPACITY];
        gate_s[tid] = v ? list_gate[e * CAPACITY + slot] : 0.f;
    }
    __syncthreads();

    const int lane = tid & 63, wave = tid >> 6;
    const int wm = wave >> 1, wn = wave & 1;
    const int fm = lane & 15, kq = lane >> 4;

    // staging maps: issue j covers rows j*32 + wave*8 + (lane>>3); granule
    // position s = lane&7 holds k-quarter q = s ^ (row&7) = (lane&7)^(lane>>3)
    const int srow = wave * 8 + (lane >> 3);
    const int q    = (lane & 7) ^ (lane >> 3);
    const unsigned short* aP[4];
    const unsigned short* bP[4];
    unsigned short* aL[4];
    unsigned short* bL[4];
#pragma unroll
    for (int j = 0; j < 4; j++) {
        int row = j * 32 + srow;
        aP[j] = xb + (size_t)tok_s[row] * DIM + q * 8;
        bP[j] = Web + ((size_t)(e * 1024 + nt * NT + row)) * DIM + q * 8;
        aL[j] = &As[row * BKF + (lane & 7) * 8];
        bL[j] = &Bs[row * BKF + (lane & 7) * 8];
    }

    f32x4 acc[4][4];
#pragma unroll
    for (int i = 0; i < 4; i++)
#pragma unroll
        for (int j = 0; j < 4; j++) acc[i][j] = (f32x4){0.f, 0.f, 0.f, 0.f};

    for (int ks = 0; ks < DIM; ks += BKF) {
        __syncthreads();
#pragma unroll
        for (int j = 0; j < 4; j++) gload_lds16(aP[j] + ks, aL[j]);
#pragma unroll
        for (int j = 0; j < 4; j++) gload_lds16(bP[j] + ks, bL[j]);
        __syncthreads();

#pragma unroll
        for (int kk = 0; kk < 2; kk++) {
            const int qq = kk * 4 + kq;
            union { uint4 u; bf16x8 v; } fa[4], fb[4];
#pragma unroll
            for (int i = 0; i < 4; i++) {
                int r = wm * 64 + i * 16 + fm;
                fa[i].u = *(const uint4*)&As[r * BKF + (qq ^ (r & 7)) * 8];
            }
#pragma unroll
            for (int j = 0; j < 4; j++) {
                int r = wn * 64 + j * 16 + fm;
                fb[j].u = *(const uint4*)&Bs[r * BKF + (qq ^ (r & 7)) * 8];
            }
#pragma unroll
            for (int i = 0; i < 4; i++)
#pragma unroll
                for (int j = 0; j < 4; j++)
                    acc[i][j] = __builtin_amdgcn_mfma_f32_16x16x32_bf16(
                        fa[i].v, fb[j].v, acc[i][j], 0, 0, 0);
        }
    }

    // epilogue: C/D layout col = lane&15, row = (lane>>4)*4 + reg
    const int col0 = nt * NT + wn * 64 + fm;
#pragma unroll
    for (int i = 0; i < 4; i++) {
        int rbase = wm * 64 + i * 16 + kq * 4;
#pragma unroll
        for (int j = 0; j < 4; j++) {
            int col = col0 + j * 16;
#pragma unroll
            for (int r = 0; r < 4; r++) {
                int row = rbase + r;
                if (row < valid) {
                    float v = acc[i][j][r];
                    v = fmaxf(v, 0.f) * gate_s[row];
                    atomicAdd(out + (size_t)tok_s[row] * DIM + col, v);
                }
            }
        }
    }
}

// ---------------------------------------------------------------------------
// Phase 3 (fallback, R1 version): used only if ws can't hold Web.
// ---------------------------------------------------------------------------
#define BK 32
#define LDA 36

__global__ __launch_bounds__(256) void moe_gemm(
    const unsigned short* __restrict__ xb, const float* __restrict__ We,
    const int* __restrict__ list_tok, const float* __restrict__ list_gate,
    const int* __restrict__ cntc, float* __restrict__ out)
{
    const int bid = blockIdx.x;
    const int e   = bid / 40;
    const int rem = bid % 40;
    const int mt  = rem >> 3;
    const int nt  = rem & 7;
    const int cnt = cntc[e];
    if (mt * MT >= cnt) return;
    int valid = cnt - mt * MT; if (valid > MT) valid = MT;

    __shared__ unsigned short As[MT * LDA];
    __shared__ unsigned short Bs[NT * LDA];
    __shared__ int   tok_s[MT];
    __shared__ float gate_s[MT];

    const int tid = threadIdx.x;
    if (tid < MT) {
        int slot = mt * MT + tid;
        bool v = tid < valid;
        tok_s[tid]  = v ? list_tok[e * CAPACITY + slot]  : list_tok[e * CAPACITY];
        gate_s[tid] = v ? list_gate[e * CAPACITY + slot] : 0.f;
    }
    __syncthreads();

    const int arow = tid >> 1, ah = tid & 1;
    const unsigned short* aptr = xb + (size_t)tok_s[arow] * DIM + ah * 16;
    const int bn0 = (tid & 31) * 4;
    const int bkr = (tid >> 5) * 4;
    const float* bptr = We + (size_t)e * DIM * DIM + (size_t)bkr * DIM + nt * NT + bn0;

    f32x4 acc[4][4];
#pragma unroll
    for (int i = 0; i < 4; i++)
#pragma unroll
        for (int j = 0; j < 4; j++) acc[i][j] = (f32x4){0.f, 0.f, 0.f, 0.f};

    const int lane = tid & 63, wave = tid >> 6;
    const int wm = wave >> 1, wn = wave & 1;
    const int fm = lane & 15, kq = lane >> 4;

    for (int ks = 0; ks < DIM; ks += BK) {
        __syncthreads();
        uint4 a0 = *(const uint4*)(aptr + ks);
        uint4 a1 = *(const uint4*)(aptr + ks + 8);
        {
            unsigned short* d = &As[arow * LDA + ah * 16];
            *(uint2*)(d + 0)  = make_uint2(a0.x, a0.y);
            *(uint2*)(d + 4)  = make_uint2(a0.z, a0.w);
            *(uint2*)(d + 8)  = make_uint2(a1.x, a1.y);
            *(uint2*)(d + 12) = make_uint2(a1.z, a1.w);
        }
        {
            float4 b[4];
#pragma unroll
            for (int j = 0; j < 4; j++)
                b[j] = *(const float4*)(bptr + (size_t)(ks + j) * DIM);
            union { float4 v; float f[4]; } u0, u1, u2, u3;
            u0.v = b[0]; u1.v = b[1]; u2.v = b[2]; u3.v = b[3];
#pragma unroll
            for (int cc = 0; cc < 4; cc++) {
                unsigned int lo = (unsigned int)f2bf(u0.f[cc]) | ((unsigned int)f2bf(u1.f[cc]) << 16);
                unsigned int hi = (unsigned int)f2bf(u2.f[cc]) | ((unsigned int)f2bf(u3.f[cc]) << 16);
                *(uint2*)&Bs[(bn0 + cc) * LDA + bkr] = make_uint2(lo, hi);
            }
        }
        __syncthreads();
        union { uint2 u[2]; bf16x8 v; } fa[4], fb[4];
#pragma unroll
        for (int i = 0; i < 4; i++) {
            const unsigned short* s = &As[(wm * 64 + i * 16 + fm) * LDA + kq * 8];
            fa[i].u[0] = *(const uint2*)(s);
            fa[i].u[1] = *(const uint2*)(s + 4);
        }
#pragma unroll
        for (int j = 0; j < 4; j++) {
            const unsigned short* s = &Bs[(wn * 64 + j * 16 + fm) * LDA + kq * 8];
            fb[j].u[0] = *(const uint2*)(s);
            fb[j].u[1] = *(const uint2*)(s + 4);
        }
#pragma unroll
        for (int i = 0; i < 4; i++)
#pragma unroll
            for (int j = 0; j < 4; j++)
                acc[i][j] = __builtin_amdgcn_mfma_f32_16x16x32_bf16(
                    fa[i].v, fb[j].v, acc[i][j], 0, 0, 0);
    }

    const int col0 = nt * NT + wn * 64 + fm;
#pragma unroll
    for (int i = 0; i < 4; i++) {
        int rbase = wm * 64 + i * 16 + kq * 4;
#pragma unroll
        for (int j = 0; j < 4; j++) {
            int col = col0 + j * 16;
#pragma unroll
            for (int r = 0; r < 4; r++) {
                int row = rbase + r;
                if (row < valid) {
                    float v = acc[i][j][r];
                    v = fmaxf(v, 0.f) * gate_s[row];
                    atomicAdd(out + (size_t)tok_s[row] * DIM + col, v);
                }
            }
        }
    }
}

// ---------------------------------------------------------------------------
extern "C" void kernel_launch(void* const* d_in, const int* in_sizes, int n_in,
                              void* d_out, int out_size, void* d_ws, size_t ws_size,
                              hipStream_t stream)
{
    const float* x  = (const float*)d_in[0];
    const float* Wr = (const float*)d_in[1];
    const float* br = (const float*)d_in[2];
    const float* We = (const float*)d_in[3];
    float* out = (float*)d_out;

    char* ws = (char*)d_ws;
    size_t off = 0;
    unsigned short* xb = (unsigned short*)(ws + off); off += (size_t)N_TOK * DIM * 2;
    int*   top2i     = (int*)(ws + off);   off += (size_t)N_TOK * 2 * 4;
    float* gates2    = (float*)(ws + off); off += (size_t)N_TOK * 2 * 4;
    int*   hist      = (int*)(ws + off);   off += 128 * NEXP * 4;
    int*   pre       = (int*)(ws + off);   off += 128 * NEXP * 4;
    int*   cntc      = (int*)(ws + off);   off += NEXP * 4;
    int*   list_tok  = (int*)(ws + off);   off += NEXP * CAPACITY * 4;
    float* list_gate = (float*)(ws + off); off += NEXP * CAPACITY * 4;
    off = (off + 255) & ~(size_t)255;
    unsigned short* Web = (unsigned short*)(ws + off);
    size_t need = off + (size_t)NEXP * DIM * DIM * 2;
    const bool fast = ws_size >= need;

    hipMemsetAsync(out, 0, (size_t)N_TOK * DIM * 4, stream);
    if (fast) convert_we<<<NEXP * 256, 256, 0, stream>>>(We, Web);
    router_kernel<<<N_TOK / 64, 256, 0, stream>>>(x, Wr, br, xb, top2i, gates2);
    hist_kernel<<<128, 256, 0, stream>>>(top2i, hist);
    scan_kernel<<<1, 64, 0, stream>>>(hist, pre, cntc);
    rank_kernel<<<128, 64, 0, stream>>>(top2i, gates2, pre, list_tok, list_gate);
    if (fast)
        moe_gemm_bt<<<NEXP * 40, 256, 0, stream>>>(xb, Web, list_tok, list_gate, cntc, out);
    else
        moe_gemm<<<NEXP * 40, 256, 0, stream>>>(xb, We, list_tok, list_gate, cntc, out);
}